// Round 9
// baseline (670.470 us; speedup 1.0000x reference)
//
#include <hip/hip_runtime.h>
#include <stdint.h>

#define HID   128
#define OUT   4096
#define NWG   8           // persistent EP workgroups, slice = 512 cols each
#define SLICE 512         // OUT / NWG
#define NT    512
#define NXB   128         // one-shot xW1 worker blocks
#define RPX   512         // rows per xW1 block (65536 / 128)
#define PDEPTH 4          // pbuf depth; 4 is the MINIMUM safe depth for the
                          // publish-before-poll pipeline (see proof in round-9 notes):
                          // overwrite of tag T needs all WGs past body T, depth 3 does not.

typedef unsigned long long u64;

__device__ __forceinline__ u64 pk(uint32_t tag, float v) {
  return ((u64)tag << 32) | (u64)__float_as_uint(v);
}

// blockIdx < NWG: persistent EP workgroup. blockIdx >= NWG: one-shot xW1 worker.
__global__ __launch_bounds__(NT, 1) void k_all(
    const float* __restrict__ x,
    const float* __restrict__ W1,
    const float* __restrict__ W2,
    const float* __restrict__ b_h,
    const float* __restrict__ b_out,
    const float* __restrict__ h0,
    const float* __restrict__ o0,
    const int* __restrict__ n_iter_p,
    const float* __restrict__ eps_p,
    u64* __restrict__ pbuf,   // [PDEPTH][NWG][HID] tagged h-gradient partials
    u64* __restrict__ xw1p,   // [NXB][HID] tagged xW1 partials
    float* __restrict__ out) {

  __shared__ __attribute__((aligned(16))) float red[8 * SLICE];  // 16 KB
  __shared__ __attribute__((aligned(16))) float ro_s[SLICE];
  __shared__ __attribute__((aligned(16))) float rh_w[8][16];     // per-wave rh strip
  __shared__ __attribute__((aligned(16))) float bhx_s[HID];
  __shared__ __attribute__((aligned(16))) float h0_s[HID];

  const int t = threadIdx.x;

  if (blockIdx.x >= NWG) {
    // ---------------- xW1 worker: partial of clip(x,0,1) @ W1 over 512 rows ------
    const int b = blockIdx.x - NWG;
    const int c4 = (t & 31) * 4;
    const int rseg = t >> 5;            // 0..15
    const int r0 = b * RPX + rseg * 32;
    float4 acc = make_float4(0.f, 0.f, 0.f, 0.f);
#pragma unroll 8
    for (int k = 0; k < 32; ++k) {
      const int r = r0 + k;
      const float rx = fminf(fmaxf(x[r], 0.f), 1.f);
      const float4 wv = *(const float4*)&W1[(size_t)r * HID + c4];
      acc.x = fmaf(rx, wv.x, acc.x); acc.y = fmaf(rx, wv.y, acc.y);
      acc.z = fmaf(rx, wv.z, acc.z); acc.w = fmaf(rx, wv.w, acc.w);
    }
    *(float4*)&red[rseg * HID + c4] = acc;
    __syncthreads();
    if (t < HID) {
      float s = 0.f;
#pragma unroll
      for (int k = 0; k < 16; k += 4)
        s += (red[k*HID + t] + red[(k+1)*HID + t]) + (red[(k+2)*HID + t] + red[(k+3)*HID + t]);
      __hip_atomic_store(&xw1p[b * HID + t], pk(1u, s),
                         __ATOMIC_RELAXED, __HIP_MEMORY_SCOPE_AGENT);
    }
    return;
  }

  // ---------------- persistent EP workgroup ---------------------------------------
  const int wg = blockIdx.x;
  const int cg = t & 63;               // lane id
  const int rg = t >> 6;               // wave id; owns h-rows rg*16 .. rg*16+15
  const int rloc = cg >> 2;            // local row within wave (0..15)
  const int q    = cg & 3;             // quad lane (polls WGs q and q+4)
  const int row  = rg * 16 + rloc;     // global h-row this lane co-owns
  const int n_iter = *n_iter_p;
  const float eps  = *eps_p;

  // ---- W2 chunk into registers: w2[r][k] = W2[rg*16+r][wg*512 + cg + 64k] ----
  float w2[16][8];
  {
    const float* wp = W2 + (size_t)(rg * 16) * OUT + wg * SLICE + cg;
#pragma unroll
    for (int r = 0; r < 16; ++r)
#pragma unroll
      for (int k = 0; k < 8; ++k)
        w2[r][k] = wp[(size_t)r * OUT + 64 * k];
  }
#pragma unroll
  for (int r = 0; r < 16; ++r)
    asm volatile("" : "+v"(w2[r][0]), "+v"(w2[r][1]), "+v"(w2[r][2]), "+v"(w2[r][3]),
                      "+v"(w2[r][4]), "+v"(w2[r][5]), "+v"(w2[r][6]), "+v"(w2[r][7]));

  // ---- startup: gather xW1 partials (batched tagged loads), fill bhx_s/h0_s ----
  if (t < HID) {
    float s = 0.f;
#pragma unroll 1
    for (int ch = 0; ch < 8; ++ch) {
      u64 v[16];
      for (;;) {
#pragma unroll
        for (int k = 0; k < 16; ++k)
          v[k] = __hip_atomic_load(&xw1p[(ch * 16 + k) * HID + t],
                                   __ATOMIC_RELAXED, __HIP_MEMORY_SCOPE_AGENT);
        uint32_t bad = 0u;
#pragma unroll
        for (int k = 0; k < 16; ++k) bad |= ((uint32_t)(v[k] >> 32)) ^ 1u;
        if (bad == 0u) break;
        __builtin_amdgcn_s_sleep(2);
      }
#pragma unroll
      for (int k = 0; k < 16; ++k) s += __uint_as_float((uint32_t)v[k]);
    }
    bhx_s[t] = b_h[t] + s;
    h0_s[t]  = h0[t];
  }
  float oo = o0[wg * SLICE + t];       // one o-column per thread (SLICE == NT)
  float mo = 0.f, vo = 0.f;
  const float bo = b_out[wg * SLICE + t];
  ro_s[t] = fminf(fmaxf(oo, 0.f), 1.f);
  __syncthreads();

  // per-lane-quad replicated h-state for row `row`
  float hh  = h0_s[row];
  float bhx = bhx_s[row];
  float mh = 0.f, vh = 0.f;
  if (q == 0) rh_w[rg][rloc] = fminf(fmaxf(hh, 0.f), 1.f);   // in-wave, no barrier

  float bp1 = 1.f, bp2 = 1.f;          // after body it: 0.9^(it+1), 0.999^(it+1)

  for (int it = 0; it < n_iter; ++it) {
    const float bph1 = bp1, bph2 = bp2;      // 0.9^it  (h bias-corr, valid it>=1)
    bp1 *= 0.9f; bp2 *= 0.999f;              // 0.9^(it+1) (o bias-corr)
    const float co1 = 1.f / (1.f - bp1);
    const float co2 = 1.f / (1.f - bp2);
    u64* pbCur  = pbuf + (size_t)(it & (PDEPTH - 1)) * (NWG * HID);
    u64* pbPrev = pbuf + (size_t)((it + PDEPTH - 1) & (PDEPTH - 1)) * (NWG * HID);
    const uint32_t tagCur  = (uint32_t)(it + 1);
    const uint32_t tagPrev = (uint32_t)it;

    // ---- issue poll loads for PREVIOUS iteration's partials (latency hides under PassB)
    u64 v0 = 0, v1 = 0;
    if (it > 0) {
      v0 = __hip_atomic_load(&pbPrev[q * HID + row],
                             __ATOMIC_RELAXED, __HIP_MEMORY_SCOPE_AGENT);
      v1 = __hip_atomic_load(&pbPrev[(q + 4) * HID + row],
                             __ATOMIC_RELAXED, __HIP_MEMORY_SCOPE_AGENT);
    }

    // ---- Pass B (registers): partial of W2 @ r_o(it) over this thread's 8 cols ----
    float aB[16];
    {
      float rov[8];
#pragma unroll
      for (int k = 0; k < 8; ++k) rov[k] = ro_s[cg + 64 * k];   // stride-1/lane, conflict-free
#pragma unroll
      for (int r = 0; r < 16; ++r) {
        float a = w2[r][0] * rov[0];
#pragma unroll
        for (int k = 1; k < 8; ++k) a = fmaf(w2[r][k], rov[k], a);
        aB[r] = a;
      }
    }
    // ---- in-wave fold: 64 lanes x 16 rows -> one row sum per lane quad ----
    {
#pragma unroll
      for (int r = 0; r < 8; ++r) {   // xor 32: 16 -> 8 rows
        const float keep = (cg & 32) ? aB[r + 8] : aB[r];
        const float send = (cg & 32) ? aB[r]     : aB[r + 8];
        aB[r] = keep + __shfl_xor(send, 32, 64);
      }
#pragma unroll
      for (int r = 0; r < 4; ++r) {   // xor 16: 8 -> 4
        const float keep = (cg & 16) ? aB[r + 4] : aB[r];
        const float send = (cg & 16) ? aB[r]     : aB[r + 4];
        aB[r] = keep + __shfl_xor(send, 16, 64);
      }
#pragma unroll
      for (int r = 0; r < 2; ++r) {   // xor 8: 4 -> 2
        const float keep = (cg & 8) ? aB[r + 2] : aB[r];
        const float send = (cg & 8) ? aB[r]     : aB[r + 2];
        aB[r] = keep + __shfl_xor(send, 8, 64);
      }
      {                               // xor 4: 2 -> 1
        const float keep = (cg & 4) ? aB[1] : aB[0];
        const float send = (cg & 4) ? aB[0] : aB[1];
        aB[0] = keep + __shfl_xor(send, 4, 64);
      }
      aB[0] += __shfl_xor(aB[0], 2, 64);   // complete the 64-lane sum
      aB[0] += __shfl_xor(aB[0], 1, 64);
    }
    // ---- publish tagged partial (tag = it+1) into slot it & 3 ----
    if (q == 0) {
      __hip_atomic_store(&pbCur[wg * HID + row], pk(tagCur, aB[0]),
                         __ATOMIC_RELAXED, __HIP_MEMORY_SCOPE_AGENT);
    }

    // ---- complete PREVIOUS poll; Adam(h) -> h(it); update rh strip (it>0) ----
    if (it > 0) {
      for (;;) {
        const bool bad = ((uint32_t)(v0 >> 32) != tagPrev) || ((uint32_t)(v1 >> 32) != tagPrev);
        if (!__any(bad)) break;
        v0 = __hip_atomic_load(&pbPrev[q * HID + row],
                               __ATOMIC_RELAXED, __HIP_MEMORY_SCOPE_AGENT);
        v1 = __hip_atomic_load(&pbPrev[(q + 4) * HID + row],
                               __ATOMIC_RELAXED, __HIP_MEMORY_SCOPE_AGENT);
      }
      // butterfly quad-sum: bitwise identical across the 4 lanes and all WGs
      float s2 = __uint_as_float((uint32_t)v0) + __uint_as_float((uint32_t)v1);
      s2 += __shfl_xor(s2, 1, 64);
      s2 += __shfl_xor(s2, 2, 64);
      const float ch1 = 1.f / (1.f - bph1);
      const float ch2 = 1.f / (1.f - bph2);
      const float rh_old = fminf(fmaxf(hh, 0.f), 1.f);
      const float g = (hh >= 0.f && hh <= 1.f) ? (rh_old - bhx - s2) : 0.f;
      mh = 0.9f * mh + 0.1f * g;
      vh = 0.999f * vh + 0.001f * g * g;
      hh -= eps * (mh * ch1) / (sqrtf(vh * ch2) + 1e-8f);
      if (q == 0) rh_w[rg][rloc] = fminf(fmaxf(hh, 0.f), 1.f);  // in-wave, no barrier
    }

    // ---- Pass A (registers): r_h(it) @ W2 over this thread's rows ----
    {
      float aA[8] = {0.f, 0.f, 0.f, 0.f, 0.f, 0.f, 0.f, 0.f};
#pragma unroll
      for (int r = 0; r < 16; ++r) {
        const float rh = rh_w[rg][r];                // own-wave broadcast, no barrier
#pragma unroll
        for (int k = 0; k < 8; ++k) aA[k] = fmaf(w2[r][k], rh, aA[k]);
      }
#pragma unroll
      for (int k = 0; k < 8; ++k)
        red[rg * SLICE + cg + 64 * k] = aA[k];       // stride-1/lane, conflict-free
    }
    __syncthreads();                                 // barrier1: red complete

    // ---- g_o + Adam(o): one column (= t) per thread -> o(it+1) ----
    {
      const float s = ((red[t] + red[SLICE + t]) + (red[2*SLICE + t] + red[3*SLICE + t]))
                    + ((red[4*SLICE + t] + red[5*SLICE + t]) + (red[6*SLICE + t] + red[7*SLICE + t]));
      const float ro_old = fminf(fmaxf(oo, 0.f), 1.f);
      const float g = (oo >= 0.f && oo <= 1.f) ? (ro_old - bo - s) : 0.f;
      mo = 0.9f * mo + 0.1f * g;
      vo = 0.999f * vo + 0.001f * g * g;
      oo -= eps * (mo * co1) / (sqrtf(vo * co2) + 1e-8f);
      ro_s[t] = fminf(fmaxf(oo, 0.f), 1.f);
    }
    __syncthreads();                                 // barrier2: ro_s complete
  }

  out[wg * SLICE + t] = oo;
}

// ---------------- launcher ----------------------------------------------------------
extern "C" void kernel_launch(void* const* d_in, const int* in_sizes, int n_in,
                              void* d_out, int out_size, void* d_ws, size_t ws_size,
                              hipStream_t stream) {
  const float* x     = (const float*)d_in[0];
  const float* W1    = (const float*)d_in[1];
  const float* W2    = (const float*)d_in[2];
  // d_in[3] = b_in (unused by the reference)
  const float* b_h   = (const float*)d_in[4];
  const float* b_out = (const float*)d_in[5];
  const float* h0    = (const float*)d_in[6];
  const float* o0    = (const float*)d_in[7];
  const int*   nit   = (const int*)d_in[8];
  const float* eps   = (const float*)d_in[9];

  u64*   pbuf = (u64*)d_ws;                         // [4][8][128] u64 = 32 KB
  u64*   xw1p = (u64*)((char*)d_ws + 32768);        // [128][128] u64 = 128 KB
  float* out  = (float*)d_out;

  // no memset needed: poisoned 0xAAAAAAAA tags never match (xw1 tag=1, iter tags=1..n)
  k_all<<<dim3(NWG + NXB), dim3(NT), 0, stream>>>(x, W1, W2, b_h, b_out, h0, o0,
                                                  nit, eps, pbuf, xw1p, out);
}

// Round 10
// 665.945 us; speedup vs baseline: 1.0068x; 1.0068x over previous
//
#include <hip/hip_runtime.h>
#include <stdint.h>

#define HID   128
#define OUT   4096
#define NWG   8           // persistent EP workgroups, slice = 512 cols each
#define SLICE 512         // OUT / NWG
#define NT    512
#define NXB   128         // one-shot xW1 worker blocks
#define RPX   512         // rows per xW1 block (65536 / 128)
#define PDEPTH 4          // min safe depth for publish-before-poll pipeline (R9 proof)

typedef unsigned long long u64;

__device__ __forceinline__ u64 pk(uint32_t tag, float v) {
  return ((u64)tag << 32) | (u64)__float_as_uint(v);
}

// LDS-only barrier: drains LDS ops (lgkmcnt) but NOT vmem (vmcnt) — keeps the
// agent-scope publish store's LLC write-through ack OFF the critical path.
// __syncthreads() would emit s_waitcnt vmcnt(0) lgkmcnt(0) and stall every wave
// on the ~0.5-1us store ack, twice per iteration.
__device__ __forceinline__ void lds_barrier() {
  asm volatile("s_waitcnt lgkmcnt(0)\n\ts_barrier" ::: "memory");
}

// blockIdx < NWG: persistent EP workgroup. blockIdx >= NWG: one-shot xW1 worker.
__global__ __launch_bounds__(NT, 1) void k_all(
    const float* __restrict__ x,
    const float* __restrict__ W1,
    const float* __restrict__ W2,
    const float* __restrict__ b_h,
    const float* __restrict__ b_out,
    const float* __restrict__ h0,
    const float* __restrict__ o0,
    const int* __restrict__ n_iter_p,
    const float* __restrict__ eps_p,
    u64* __restrict__ pbuf,   // [PDEPTH][NWG][HID] tagged h-gradient partials
    u64* __restrict__ xw1p,   // [NXB][HID] tagged xW1 partials
    float* __restrict__ out) {

  __shared__ __attribute__((aligned(16))) float red[8 * SLICE];  // 16 KB
  __shared__ __attribute__((aligned(16))) float ro_s[SLICE];
  __shared__ __attribute__((aligned(16))) float rh_w[8][16];     // per-wave rh strip
  __shared__ __attribute__((aligned(16))) float bhx_s[HID];
  __shared__ __attribute__((aligned(16))) float h0_s[HID];

  const int t = threadIdx.x;

  if (blockIdx.x >= NWG) {
    // ---------------- xW1 worker: partial of clip(x,0,1) @ W1 over 512 rows ------
    const int b = blockIdx.x - NWG;
    const int c4 = (t & 31) * 4;
    const int rseg = t >> 5;            // 0..15
    const int r0 = b * RPX + rseg * 32;
    float4 acc = make_float4(0.f, 0.f, 0.f, 0.f);
#pragma unroll 8
    for (int k = 0; k < 32; ++k) {
      const int r = r0 + k;
      const float rx = fminf(fmaxf(x[r], 0.f), 1.f);
      const float4 wv = *(const float4*)&W1[(size_t)r * HID + c4];
      acc.x = fmaf(rx, wv.x, acc.x); acc.y = fmaf(rx, wv.y, acc.y);
      acc.z = fmaf(rx, wv.z, acc.z); acc.w = fmaf(rx, wv.w, acc.w);
    }
    *(float4*)&red[rseg * HID + c4] = acc;
    __syncthreads();
    if (t < HID) {
      float s = 0.f;
#pragma unroll
      for (int k = 0; k < 16; k += 4)
        s += (red[k*HID + t] + red[(k+1)*HID + t]) + (red[(k+2)*HID + t] + red[(k+3)*HID + t]);
      __hip_atomic_store(&xw1p[b * HID + t], pk(1u, s),
                         __ATOMIC_RELAXED, __HIP_MEMORY_SCOPE_AGENT);
    }
    return;
  }

  // ---------------- persistent EP workgroup ---------------------------------------
  const int wg = blockIdx.x;
  const int cg = t & 63;               // lane id
  const int rg = t >> 6;               // wave id; owns h-rows rg*16 .. rg*16+15
  const int rloc = cg >> 2;            // local row within wave (0..15)
  const int q    = cg & 3;             // quad lane (polls WGs q and q+4)
  const int row  = rg * 16 + rloc;     // global h-row this lane co-owns
  const int n_iter = *n_iter_p;
  const float eps  = *eps_p;

  // ---- W2 chunk into registers: w2[r][k] = W2[rg*16+r][wg*512 + cg + 64k] ----
  float w2[16][8];
  {
    const float* wp = W2 + (size_t)(rg * 16) * OUT + wg * SLICE + cg;
#pragma unroll
    for (int r = 0; r < 16; ++r)
#pragma unroll
      for (int k = 0; k < 8; ++k)
        w2[r][k] = wp[(size_t)r * OUT + 64 * k];
  }
#pragma unroll
  for (int r = 0; r < 16; ++r)
    asm volatile("" : "+v"(w2[r][0]), "+v"(w2[r][1]), "+v"(w2[r][2]), "+v"(w2[r][3]),
                      "+v"(w2[r][4]), "+v"(w2[r][5]), "+v"(w2[r][6]), "+v"(w2[r][7]));

  // ---- startup: gather xW1 partials (batched tagged loads), fill bhx_s/h0_s ----
  if (t < HID) {
    float s = 0.f;
#pragma unroll 1
    for (int ch = 0; ch < 8; ++ch) {
      u64 v[16];
      for (;;) {
#pragma unroll
        for (int k = 0; k < 16; ++k)
          v[k] = __hip_atomic_load(&xw1p[(ch * 16 + k) * HID + t],
                                   __ATOMIC_RELAXED, __HIP_MEMORY_SCOPE_AGENT);
        uint32_t bad = 0u;
#pragma unroll
        for (int k = 0; k < 16; ++k) bad |= ((uint32_t)(v[k] >> 32)) ^ 1u;
        if (bad == 0u) break;
        __builtin_amdgcn_s_sleep(2);
      }
#pragma unroll
      for (int k = 0; k < 16; ++k) s += __uint_as_float((uint32_t)v[k]);
    }
    bhx_s[t] = b_h[t] + s;
    h0_s[t]  = h0[t];
  }
  float oo = o0[wg * SLICE + t];       // one o-column per thread (SLICE == NT)
  float mo = 0.f, vo = 0.f;
  const float bo = b_out[wg * SLICE + t];
  ro_s[t] = fminf(fmaxf(oo, 0.f), 1.f);
  __syncthreads();                     // startup only — full drain is fine here

  // per-lane-quad replicated h-state for row `row`
  float hh  = h0_s[row];
  float bhx = bhx_s[row];
  float mh = 0.f, vh = 0.f;
  if (q == 0) rh_w[rg][rloc] = fminf(fmaxf(hh, 0.f), 1.f);   // in-wave, no barrier

  float bp1 = 1.f, bp2 = 1.f;          // after body it: 0.9^(it+1), 0.999^(it+1)

  for (int it = 0; it < n_iter; ++it) {
    const float bph1 = bp1, bph2 = bp2;      // 0.9^it  (h bias-corr, valid it>=1)
    bp1 *= 0.9f; bp2 *= 0.999f;              // 0.9^(it+1) (o bias-corr)
    const float co1 = 1.f / (1.f - bp1);
    const float co2 = 1.f / (1.f - bp2);
    u64* pbCur  = pbuf + (size_t)(it & (PDEPTH - 1)) * (NWG * HID);
    u64* pbPrev = pbuf + (size_t)((it + PDEPTH - 1) & (PDEPTH - 1)) * (NWG * HID);
    const uint32_t tagCur  = (uint32_t)(it + 1);
    const uint32_t tagPrev = (uint32_t)it;

    // ---- issue poll loads for PREVIOUS iteration's partials (latency hides under PassB)
    u64 v0 = 0, v1 = 0;
    if (it > 0) {
      v0 = __hip_atomic_load(&pbPrev[q * HID + row],
                             __ATOMIC_RELAXED, __HIP_MEMORY_SCOPE_AGENT);
      v1 = __hip_atomic_load(&pbPrev[(q + 4) * HID + row],
                             __ATOMIC_RELAXED, __HIP_MEMORY_SCOPE_AGENT);
    }

    // ---- Pass B (registers): partial of W2 @ r_o(it) over this thread's 8 cols ----
    float aB[16];
    {
      float rov[8];
#pragma unroll
      for (int k = 0; k < 8; ++k) rov[k] = ro_s[cg + 64 * k];   // stride-1/lane, conflict-free
#pragma unroll
      for (int r = 0; r < 16; ++r) {
        float a = w2[r][0] * rov[0];
#pragma unroll
        for (int k = 1; k < 8; ++k) a = fmaf(w2[r][k], rov[k], a);
        aB[r] = a;
      }
    }
    // ---- in-wave fold: 64 lanes x 16 rows -> one row sum per lane quad ----
    {
#pragma unroll
      for (int r = 0; r < 8; ++r) {   // xor 32: 16 -> 8 rows
        const float keep = (cg & 32) ? aB[r + 8] : aB[r];
        const float send = (cg & 32) ? aB[r]     : aB[r + 8];
        aB[r] = keep + __shfl_xor(send, 32, 64);
      }
#pragma unroll
      for (int r = 0; r < 4; ++r) {   // xor 16: 8 -> 4
        const float keep = (cg & 16) ? aB[r + 4] : aB[r];
        const float send = (cg & 16) ? aB[r]     : aB[r + 4];
        aB[r] = keep + __shfl_xor(send, 16, 64);
      }
#pragma unroll
      for (int r = 0; r < 2; ++r) {   // xor 8: 4 -> 2
        const float keep = (cg & 8) ? aB[r + 2] : aB[r];
        const float send = (cg & 8) ? aB[r]     : aB[r + 2];
        aB[r] = keep + __shfl_xor(send, 8, 64);
      }
      {                               // xor 4: 2 -> 1
        const float keep = (cg & 4) ? aB[1] : aB[0];
        const float send = (cg & 4) ? aB[0] : aB[1];
        aB[0] = keep + __shfl_xor(send, 4, 64);
      }
      aB[0] += __shfl_xor(aB[0], 2, 64);   // complete the 64-lane sum
      aB[0] += __shfl_xor(aB[0], 1, 64);
    }
    // ---- publish tagged partial (tag = it+1) into slot it & 3; ack drains lazily ----
    if (q == 0) {
      __hip_atomic_store(&pbCur[wg * HID + row], pk(tagCur, aB[0]),
                         __ATOMIC_RELAXED, __HIP_MEMORY_SCOPE_AGENT);
    }

    // ---- complete PREVIOUS poll; Adam(h) -> h(it); update rh strip (it>0) ----
    if (it > 0) {
      for (;;) {
        const bool bad = ((uint32_t)(v0 >> 32) != tagPrev) || ((uint32_t)(v1 >> 32) != tagPrev);
        if (!__any(bad)) break;
        v0 = __hip_atomic_load(&pbPrev[q * HID + row],
                               __ATOMIC_RELAXED, __HIP_MEMORY_SCOPE_AGENT);
        v1 = __hip_atomic_load(&pbPrev[(q + 4) * HID + row],
                               __ATOMIC_RELAXED, __HIP_MEMORY_SCOPE_AGENT);
      }
      // butterfly quad-sum: bitwise identical across the 4 lanes and all WGs
      float s2 = __uint_as_float((uint32_t)v0) + __uint_as_float((uint32_t)v1);
      s2 += __shfl_xor(s2, 1, 64);
      s2 += __shfl_xor(s2, 2, 64);
      const float ch1 = 1.f / (1.f - bph1);
      const float ch2 = 1.f / (1.f - bph2);
      const float rh_old = fminf(fmaxf(hh, 0.f), 1.f);
      const float g = (hh >= 0.f && hh <= 1.f) ? (rh_old - bhx - s2) : 0.f;
      mh = 0.9f * mh + 0.1f * g;
      vh = 0.999f * vh + 0.001f * g * g;
      hh -= eps * (mh * ch1) / (sqrtf(vh * ch2) + 1e-8f);
      if (q == 0) rh_w[rg][rloc] = fminf(fmaxf(hh, 0.f), 1.f);  // in-wave, no barrier
    }

    // ---- Pass A (registers): r_h(it) @ W2 over this thread's rows ----
    {
      float aA[8] = {0.f, 0.f, 0.f, 0.f, 0.f, 0.f, 0.f, 0.f};
#pragma unroll
      for (int r = 0; r < 16; ++r) {
        const float rh = rh_w[rg][r];                // own-wave broadcast, no barrier
#pragma unroll
        for (int k = 0; k < 8; ++k) aA[k] = fmaf(w2[r][k], rh, aA[k]);
      }
#pragma unroll
      for (int k = 0; k < 8; ++k)
        red[rg * SLICE + cg + 64 * k] = aA[k];       // stride-1/lane, conflict-free
    }
    lds_barrier();                                   // barrier1: red complete (LDS only)

    // ---- g_o + Adam(o): one column (= t) per thread -> o(it+1) ----
    {
      const float s = ((red[t] + red[SLICE + t]) + (red[2*SLICE + t] + red[3*SLICE + t]))
                    + ((red[4*SLICE + t] + red[5*SLICE + t]) + (red[6*SLICE + t] + red[7*SLICE + t]));
      const float ro_old = fminf(fmaxf(oo, 0.f), 1.f);
      const float g = (oo >= 0.f && oo <= 1.f) ? (ro_old - bo - s) : 0.f;
      mo = 0.9f * mo + 0.1f * g;
      vo = 0.999f * vo + 0.001f * g * g;
      oo -= eps * (mo * co1) / (sqrtf(vo * co2) + 1e-8f);
      ro_s[t] = fminf(fmaxf(oo, 0.f), 1.f);
    }
    lds_barrier();                                   // barrier2: ro_s complete (LDS only)
  }

  out[wg * SLICE + t] = oo;
}

// ---------------- launcher ----------------------------------------------------------
extern "C" void kernel_launch(void* const* d_in, const int* in_sizes, int n_in,
                              void* d_out, int out_size, void* d_ws, size_t ws_size,
                              hipStream_t stream) {
  const float* x     = (const float*)d_in[0];
  const float* W1    = (const float*)d_in[1];
  const float* W2    = (const float*)d_in[2];
  // d_in[3] = b_in (unused by the reference)
  const float* b_h   = (const float*)d_in[4];
  const float* b_out = (const float*)d_in[5];
  const float* h0    = (const float*)d_in[6];
  const float* o0    = (const float*)d_in[7];
  const int*   nit   = (const int*)d_in[8];
  const float* eps   = (const float*)d_in[9];

  u64*   pbuf = (u64*)d_ws;                         // [4][8][128] u64 = 32 KB
  u64*   xw1p = (u64*)((char*)d_ws + 32768);        // [128][128] u64 = 128 KB
  float* out  = (float*)d_out;

  // no memset needed: poisoned 0xAAAAAAAA tags never match (xw1 tag=1, iter tags=1..n)
  k_all<<<dim3(NWG + NXB), dim3(NT), 0, stream>>>(x, W1, W2, b_h, b_out, h0, o0,
                                                  nit, eps, pbuf, xw1p, out);
}

// Round 11
// 609.668 us; speedup vs baseline: 1.0997x; 1.0923x over previous
//
#include <hip/hip_runtime.h>
#include <stdint.h>

#define HID   128
#define OUT   4096
#define NWG   16          // persistent EP workgroups, slice = 256 cols each
#define SLICE 256         // OUT / NWG
#define NT    512
#define NXB   128         // one-shot xW1 worker blocks
#define RPX   512         // rows per xW1 block (65536 / 128)
#define PDEPTH 4          // min safe depth for publish-before-poll pipeline (R9 proof)

typedef unsigned long long u64;

__device__ __forceinline__ u64 pk(uint32_t tag, float v) {
  return ((u64)tag << 32) | (u64)__float_as_uint(v);
}

// LDS-only barrier (keeps the agent-scope publish ack off the critical path).
__device__ __forceinline__ void lds_barrier() {
  asm volatile("s_waitcnt lgkmcnt(0)\n\ts_barrier" ::: "memory");
}

// blockIdx < NWG: persistent EP workgroup. blockIdx >= NWG: one-shot xW1 worker.
__global__ __launch_bounds__(NT, 1) void k_all(
    const float* __restrict__ x,
    const float* __restrict__ W1,
    const float* __restrict__ W2,
    const float* __restrict__ b_h,
    const float* __restrict__ b_out,
    const float* __restrict__ h0,
    const float* __restrict__ o0,
    const int* __restrict__ n_iter_p,
    const float* __restrict__ eps_p,
    u64* __restrict__ pbuf,   // [PDEPTH][NWG][HID] tagged h-gradient partials
    u64* __restrict__ xw1p,   // [NXB][HID] tagged xW1 partials
    float* __restrict__ out) {

  __shared__ __attribute__((aligned(16))) float red[8 * SLICE];  // 8 KB (workers reuse: 16*HID)
  __shared__ __attribute__((aligned(16))) float ro_s[SLICE];
  __shared__ __attribute__((aligned(16))) float rh_w[8][16];     // per-wave rh strip
  __shared__ __attribute__((aligned(16))) float bhx_s[HID];
  __shared__ __attribute__((aligned(16))) float h0_s[HID];

  const int t = threadIdx.x;

  if (blockIdx.x >= NWG) {
    // ---------------- xW1 worker: partial of clip(x,0,1) @ W1 over 512 rows ------
    const int b = blockIdx.x - NWG;
    const int c4 = (t & 31) * 4;
    const int rseg = t >> 5;            // 0..15
    const int r0 = b * RPX + rseg * 32;
    float4 acc = make_float4(0.f, 0.f, 0.f, 0.f);
#pragma unroll 8
    for (int k = 0; k < 32; ++k) {
      const int r = r0 + k;
      const float rx = fminf(fmaxf(x[r], 0.f), 1.f);
      const float4 wv = *(const float4*)&W1[(size_t)r * HID + c4];
      acc.x = fmaf(rx, wv.x, acc.x); acc.y = fmaf(rx, wv.y, acc.y);
      acc.z = fmaf(rx, wv.z, acc.z); acc.w = fmaf(rx, wv.w, acc.w);
    }
    *(float4*)&red[rseg * HID + c4] = acc;   // 16*128 = 2048 floats, fits exactly
    __syncthreads();
    if (t < HID) {
      float s = 0.f;
#pragma unroll
      for (int k = 0; k < 16; k += 4)
        s += (red[k*HID + t] + red[(k+1)*HID + t]) + (red[(k+2)*HID + t] + red[(k+3)*HID + t]);
      __hip_atomic_store(&xw1p[b * HID + t], pk(1u, s),
                         __ATOMIC_RELAXED, __HIP_MEMORY_SCOPE_AGENT);
    }
    return;
  }

  // ---------------- persistent EP workgroup ---------------------------------------
  const int wg = blockIdx.x;
  const int cg = t & 63;               // lane id; owns cols cg + 64*k (k=0..3)
  const int rg = t >> 6;               // wave id; owns h-rows rg*16 .. rg*16+15
  const int rloc = cg >> 2;            // local row within wave (0..15)
  const int q    = cg & 3;             // quad lane (polls WGs q, q+4, q+8, q+12)
  const int row  = rg * 16 + rloc;     // global h-row this lane co-owns
  const int n_iter = *n_iter_p;
  const float eps  = *eps_p;

  // ---- W2 chunk into registers: w2[r][k] = W2[rg*16+r][wg*256 + cg + 64k] ----
  float w2[16][4];
  {
    const float* wp = W2 + (size_t)(rg * 16) * OUT + wg * SLICE + cg;
#pragma unroll
    for (int r = 0; r < 16; ++r)
#pragma unroll
      for (int k = 0; k < 4; ++k)
        w2[r][k] = wp[(size_t)r * OUT + 64 * k];
  }
#pragma unroll
  for (int r = 0; r < 16; ++r)
    asm volatile("" : "+v"(w2[r][0]), "+v"(w2[r][1]), "+v"(w2[r][2]), "+v"(w2[r][3]));

  // ---- startup: gather xW1 partials (batched tagged loads), fill bhx_s/h0_s ----
  if (t < HID) {
    float s = 0.f;
#pragma unroll 1
    for (int ch = 0; ch < 8; ++ch) {
      u64 v[16];
      for (;;) {
#pragma unroll
        for (int k = 0; k < 16; ++k)
          v[k] = __hip_atomic_load(&xw1p[(ch * 16 + k) * HID + t],
                                   __ATOMIC_RELAXED, __HIP_MEMORY_SCOPE_AGENT);
        uint32_t bad = 0u;
#pragma unroll
        for (int k = 0; k < 16; ++k) bad |= ((uint32_t)(v[k] >> 32)) ^ 1u;
        if (bad == 0u) break;
        __builtin_amdgcn_s_sleep(2);
      }
#pragma unroll
      for (int k = 0; k < 16; ++k) s += __uint_as_float((uint32_t)v[k]);
    }
    bhx_s[t] = b_h[t] + s;
    h0_s[t]  = h0[t];
  }
  float oo = 0.f, mo = 0.f, vo = 0.f, bo = 0.f;
  if (t < SLICE) {
    oo = o0[wg * SLICE + t];
    bo = b_out[wg * SLICE + t];
    ro_s[t] = fminf(fmaxf(oo, 0.f), 1.f);
  }
  __syncthreads();                     // startup only

  // per-lane-quad replicated h-state for row `row`
  float hh  = h0_s[row];
  float bhx = bhx_s[row];
  float mh = 0.f, vh = 0.f;
  if (q == 0) rh_w[rg][rloc] = fminf(fmaxf(hh, 0.f), 1.f);   // in-wave, no barrier

  float bp1 = 1.f, bp2 = 1.f;          // after body it: 0.9^(it+1), 0.999^(it+1)

  for (int it = 0; it < n_iter; ++it) {
    const float bph1 = bp1, bph2 = bp2;      // 0.9^it  (h bias-corr, valid it>=1)
    bp1 *= 0.9f; bp2 *= 0.999f;              // 0.9^(it+1) (o bias-corr)
    const float co1 = 1.f / (1.f - bp1);
    const float co2 = 1.f / (1.f - bp2);
    u64* pbCur  = pbuf + (size_t)(it & (PDEPTH - 1)) * (NWG * HID);
    u64* pbPrev = pbuf + (size_t)((it + PDEPTH - 1) & (PDEPTH - 1)) * (NWG * HID);
    const uint32_t tagCur  = (uint32_t)(it + 1);
    const uint32_t tagPrev = (uint32_t)it;

    // ---- issue poll loads for PREVIOUS iteration's partials (first-try hit) ----
    u64 v0 = 0, v1 = 0, v2 = 0, v3 = 0;
    if (it > 0) {
      v0 = __hip_atomic_load(&pbPrev[(q     ) * HID + row], __ATOMIC_RELAXED, __HIP_MEMORY_SCOPE_AGENT);
      v1 = __hip_atomic_load(&pbPrev[(q +  4) * HID + row], __ATOMIC_RELAXED, __HIP_MEMORY_SCOPE_AGENT);
      v2 = __hip_atomic_load(&pbPrev[(q +  8) * HID + row], __ATOMIC_RELAXED, __HIP_MEMORY_SCOPE_AGENT);
      v3 = __hip_atomic_load(&pbPrev[(q + 12) * HID + row], __ATOMIC_RELAXED, __HIP_MEMORY_SCOPE_AGENT);
    }

    // ---- Pass B (registers): partial of W2 @ r_o(it) over this thread's 4 cols ----
    float aB[16];
    {
      float rov[4];
#pragma unroll
      for (int k = 0; k < 4; ++k) rov[k] = ro_s[cg + 64 * k];   // stride-1/lane, conflict-free
#pragma unroll
      for (int r = 0; r < 16; ++r) {
        float a = w2[r][0] * rov[0];
#pragma unroll
        for (int k = 1; k < 4; ++k) a = fmaf(w2[r][k], rov[k], a);
        aB[r] = a;
      }
    }
    // ---- in-wave fold: 64 lanes x 16 rows -> one row sum per lane quad ----
    {
#pragma unroll
      for (int r = 0; r < 8; ++r) {   // xor 32: 16 -> 8 rows
        const float keep = (cg & 32) ? aB[r + 8] : aB[r];
        const float send = (cg & 32) ? aB[r]     : aB[r + 8];
        aB[r] = keep + __shfl_xor(send, 32, 64);
      }
#pragma unroll
      for (int r = 0; r < 4; ++r) {   // xor 16: 8 -> 4
        const float keep = (cg & 16) ? aB[r + 4] : aB[r];
        const float send = (cg & 16) ? aB[r]     : aB[r + 4];
        aB[r] = keep + __shfl_xor(send, 16, 64);
      }
#pragma unroll
      for (int r = 0; r < 2; ++r) {   // xor 8: 4 -> 2
        const float keep = (cg & 8) ? aB[r + 2] : aB[r];
        const float send = (cg & 8) ? aB[r]     : aB[r + 2];
        aB[r] = keep + __shfl_xor(send, 8, 64);
      }
      {                               // xor 4: 2 -> 1
        const float keep = (cg & 4) ? aB[1] : aB[0];
        const float send = (cg & 4) ? aB[0] : aB[1];
        aB[0] = keep + __shfl_xor(send, 4, 64);
      }
      aB[0] += __shfl_xor(aB[0], 2, 64);   // complete the 64-lane sum
      aB[0] += __shfl_xor(aB[0], 1, 64);
    }
    // ---- publish tagged partial (tag = it+1) into slot it & 3 ----
    if (q == 0) {
      __hip_atomic_store(&pbCur[wg * HID + row], pk(tagCur, aB[0]),
                         __ATOMIC_RELAXED, __HIP_MEMORY_SCOPE_AGENT);
    }

    // ---- complete PREVIOUS poll; Adam(h) -> h(it); update rh strip (it>0) ----
    if (it > 0) {
      for (;;) {
        const bool bad = ((uint32_t)(v0 >> 32) != tagPrev) || ((uint32_t)(v1 >> 32) != tagPrev)
                      || ((uint32_t)(v2 >> 32) != tagPrev) || ((uint32_t)(v3 >> 32) != tagPrev);
        if (!__any(bad)) break;
        v0 = __hip_atomic_load(&pbPrev[(q     ) * HID + row], __ATOMIC_RELAXED, __HIP_MEMORY_SCOPE_AGENT);
        v1 = __hip_atomic_load(&pbPrev[(q +  4) * HID + row], __ATOMIC_RELAXED, __HIP_MEMORY_SCOPE_AGENT);
        v2 = __hip_atomic_load(&pbPrev[(q +  8) * HID + row], __ATOMIC_RELAXED, __HIP_MEMORY_SCOPE_AGENT);
        v3 = __hip_atomic_load(&pbPrev[(q + 12) * HID + row], __ATOMIC_RELAXED, __HIP_MEMORY_SCOPE_AGENT);
      }
      // fixed-order lane sum, then commutative butterfly: bitwise identical everywhere
      float s2 = (__uint_as_float((uint32_t)v0) + __uint_as_float((uint32_t)v1))
               + (__uint_as_float((uint32_t)v2) + __uint_as_float((uint32_t)v3));
      s2 += __shfl_xor(s2, 1, 64);
      s2 += __shfl_xor(s2, 2, 64);
      const float ch1 = 1.f / (1.f - bph1);
      const float ch2 = 1.f / (1.f - bph2);
      const float rh_old = fminf(fmaxf(hh, 0.f), 1.f);
      const float g = (hh >= 0.f && hh <= 1.f) ? (rh_old - bhx - s2) : 0.f;
      mh = 0.9f * mh + 0.1f * g;
      vh = 0.999f * vh + 0.001f * g * g;
      hh -= eps * (mh * ch1) / (sqrtf(vh * ch2) + 1e-8f);
      if (q == 0) rh_w[rg][rloc] = fminf(fmaxf(hh, 0.f), 1.f);  // in-wave, no barrier
    }

    // ---- Pass A (registers): r_h(it) @ W2 over this thread's rows ----
    {
      float aA[4] = {0.f, 0.f, 0.f, 0.f};
#pragma unroll
      for (int r = 0; r < 16; ++r) {
        const float rh = rh_w[rg][r];                // own-wave broadcast, no barrier
#pragma unroll
        for (int k = 0; k < 4; ++k) aA[k] = fmaf(w2[r][k], rh, aA[k]);
      }
#pragma unroll
      for (int k = 0; k < 4; ++k)
        red[rg * SLICE + cg + 64 * k] = aA[k];       // stride-1/lane, conflict-free
    }
    lds_barrier();                                   // barrier1: red complete

    // ---- g_o + Adam(o): one column per thread t < SLICE -> o(it+1) ----
    if (t < SLICE) {
      const float s = ((red[t] + red[SLICE + t]) + (red[2*SLICE + t] + red[3*SLICE + t]))
                    + ((red[4*SLICE + t] + red[5*SLICE + t]) + (red[6*SLICE + t] + red[7*SLICE + t]));
      const float ro_old = fminf(fmaxf(oo, 0.f), 1.f);
      const float g = (oo >= 0.f && oo <= 1.f) ? (ro_old - bo - s) : 0.f;
      mo = 0.9f * mo + 0.1f * g;
      vo = 0.999f * vo + 0.001f * g * g;
      oo -= eps * (mo * co1) / (sqrtf(vo * co2) + 1e-8f);
      ro_s[t] = fminf(fmaxf(oo, 0.f), 1.f);
    }
    lds_barrier();                                   // barrier2: ro_s complete
  }

  if (t < SLICE) out[wg * SLICE + t] = oo;
}

// ---------------- launcher ----------------------------------------------------------
extern "C" void kernel_launch(void* const* d_in, const int* in_sizes, int n_in,
                              void* d_out, int out_size, void* d_ws, size_t ws_size,
                              hipStream_t stream) {
  const float* x     = (const float*)d_in[0];
  const float* W1    = (const float*)d_in[1];
  const float* W2    = (const float*)d_in[2];
  // d_in[3] = b_in (unused by the reference)
  const float* b_h   = (const float*)d_in[4];
  const float* b_out = (const float*)d_in[5];
  const float* h0    = (const float*)d_in[6];
  const float* o0    = (const float*)d_in[7];
  const int*   nit   = (const int*)d_in[8];
  const float* eps   = (const float*)d_in[9];

  u64*   pbuf = (u64*)d_ws;                         // [4][16][128] u64 = 64 KB
  u64*   xw1p = (u64*)((char*)d_ws + 65536);        // [128][128] u64 = 128 KB
  float* out  = (float*)d_out;

  // no memset needed: poisoned 0xAAAAAAAA tags never match (xw1 tag=1, iter tags=1..n)
  k_all<<<dim3(NWG + NXB), dim3(NT), 0, stream>>>(x, W1, W2, b_h, b_out, h0, o0,
                                                  nit, eps, pbuf, xw1p, out);
}